// Round 3
// baseline (361.849 us; speedup 1.0000x reference)
//
#include <hip/hip_runtime.h>

#define B_N 8192
#define C_N 20000
#define D_N 128
#define CPAD 20096              // 157 * 128
#define NTILES 157
#define NSPLIT 16
#define MARGIN_F 0.15001125f    // 0.15 + (1/40000)*(0.6-0.15)

typedef __attribute__((ext_vector_type(8))) short bf16x8;
typedef __attribute__((ext_vector_type(4))) float f32x4;

typedef __attribute__((address_space(1))) const unsigned int GUint;
typedef __attribute__((address_space(3))) unsigned int LUint;

__device__ __forceinline__ unsigned short f2bf(float x) {
    union { float f; unsigned int u; } v; v.f = x;
    unsigned int r = v.u + 0x7fffu + ((v.u >> 16) & 1u);
    return (unsigned short)(r >> 16);
}
__device__ __forceinline__ float bf2f(unsigned short h) {
    union { unsigned int u; float f; } v; v.u = ((unsigned int)h) << 16; return v.f;
}

// ---- kernel 1: normalize features -> bf16, t[b] = MARGIN - posdot.
// Corrections (label column always counted in k_main; 96 zero-pad columns each
// contribute loss = t[b]) are atomically SUBTRACTED from the global accumulators.
__global__ __launch_bounds__(256) void k_normalize(
    const float* __restrict__ feat, const float* __restrict__ centers,
    const int* __restrict__ labels, unsigned short* __restrict__ fb,
    float* __restrict__ t, float* __restrict__ acc_total, unsigned int* __restrict__ acc_cnt)
{
    const int lane = threadIdx.x & 63;
    const int row  = blockIdx.x * 4 + (threadIdx.x >> 6);   // wave per row
    const float2 fv = *(const float2*)(feat + (size_t)row * D_N + lane * 2);
    float ss = fv.x * fv.x + fv.y * fv.y;
    #pragma unroll
    for (int off = 32; off; off >>= 1) ss += __shfl_xor(ss, off);
    const float scale = 1.0f / fmaxf(sqrtf(ss), 1e-12f);
    const float a = fv.x * scale, b = fv.y * scale;
    ushort2 o; o.x = f2bf(a); o.y = f2bf(b);
    *(ushort2*)(fb + (size_t)row * D_N + lane * 2) = o;

    const int lab = labels[row];
    const float2 cv = *(const float2*)(centers + (size_t)lab * D_N + lane * 2);
    float pd = a * cv.x + b * cv.y;                                   // fp32 dot
    float pb = bf2f(o.x) * bf2f(f2bf(cv.x)) + bf2f(o.y) * bf2f(f2bf(cv.y)); // bf16 dot
    #pragma unroll
    for (int off = 32; off; off >>= 1) {
        pd += __shfl_xor(pd, off);
        pb += __shfl_xor(pb, off);
    }
    if (lane == 0) {
        const float tb = MARGIN_F - pd;
        t[row] = tb;
        float cs = fmaxf(tb + pb, 0.0f);                 // label-column term
        unsigned int cc = (tb + pb > 0.0f) ? 1u : 0u;
        if (tb > 0.0f) { cs += 96.0f * tb; cc += 96u; }  // padded columns
        atomicAdd(acc_total, -cs);
        atomicAdd(acc_cnt, (unsigned int)(-(int)cc));
    }
}

// ---- kernel 2: centers -> bf16, zero-pad rows [20000,20096) ----
__global__ __launch_bounds__(256) void k_convert(
    const float* __restrict__ centers, unsigned short* __restrict__ cb)
{
    const int idx = blockIdx.x * 256 + threadIdx.x;
    const int e = idx * 4;
    const int row = e >> 7;
    ushort4 o;
    if (row < C_N) {
        const float4 v = *(const float4*)(centers + e);
        o.x = f2bf(v.x); o.y = f2bf(v.y); o.z = f2bf(v.z); o.w = f2bf(v.w);
    } else {
        o.x = 0; o.y = 0; o.z = 0; o.w = 0;
    }
    *(ushort4*)(cb + e) = o;
}

// ---- kernel 3: main. 256 feature rows per block, features in regs (B-operand),
// centers double-buffered in LDS (A-operand). 8 waves (4 feat x 2 cent), 64x64
// wave tile, 16x16x32 bf16 MFMA. acc initialized to t[m] so MFMA yields loss.
__global__ __launch_bounds__(512, 4) void k_main(
    const unsigned short* __restrict__ fb,   // [8192][128] bf16 normalized features
    const unsigned short* __restrict__ cb,   // [20096][128] bf16 centers, zero-padded
    const float* __restrict__ t,             // [8192]
    float* __restrict__ acc_total, unsigned int* __restrict__ acc_cnt)
{
    __shared__ __align__(16) unsigned short sB[2][128 * 128];   // 2 x 32 KB
    __shared__ float sWsum[8];
    __shared__ unsigned int sWcnt[8];

    const int tid  = threadIdx.x;
    const int lane = tid & 63;
    const int w    = tid >> 6;            // wave 0..7
    const int chunk   = blockIdx.x;       // 0..15, processes tiles chunk + 16j
    const int rowbase = blockIdx.y * 256; // feature row block
    const int nt = (156 - chunk) / 16 + 1;

    const int wc = (w & 1) * 64;          // wave center-col offset
    const int wf = (w >> 1) * 64;         // wave feature-row offset
    const int l15 = lane & 15;
    const int kg  = lane >> 4;

    // ---- prologue: feature fragments + t values -> registers ----
    bf16x8 ffr[4][4];                     // [ks][ff]
    float tvr[4];
    #pragma unroll
    for (int ff = 0; ff < 4; ++ff) {
        const int m = rowbase + wf + ff * 16 + l15;
        const unsigned short* src = fb + (size_t)m * D_N + kg * 8;
        #pragma unroll
        for (int ks = 0; ks < 4; ++ks)
            ffr[ks][ff] = *(const bf16x8*)(src + ks * 32);
        tvr[ff] = t[m];
    }

    // ---- center staging: linear LDS dest + involution-swizzled global source ----
    const char* gB0 = (const char*)cb;
    auto STAGE = [&](int buf, int tile) {
        const char* gB = gB0 + (size_t)tile * 32768;
        const int base = w * 4096;
        #pragma unroll
        for (int i = 0; i < 4; ++i) {
            const int loff = base + i * 1024;              // wave-uniform LDS base
            const int x = loff + lane * 16;
            const int sx = x ^ (((x >> 8) & 7) << 4);      // involution
            __builtin_amdgcn_global_load_lds((GUint*)(gB + sx),
                (LUint*)((char*)sB[buf] + loff), 16, 0, 0);
        }
    };

    STAGE(0, chunk);
    __syncthreads();

    float lsum = 0.0f;
    unsigned int wcnt = 0;

    for (int j = 0; j < nt; ++j) {
        const int cur = j & 1;
        if (j + 1 < nt) STAGE(cur ^ 1, chunk + (j + 1) * 16);   // prefetch

        f32x4 acc[4][4];                  // [fc][ff]
        #pragma unroll
        for (int fc = 0; fc < 4; ++fc)
            #pragma unroll
            for (int ff = 0; ff < 4; ++ff)
                #pragma unroll
                for (int r = 0; r < 4; ++r)
                    acc[fc][ff][r] = tvr[ff];

        #pragma unroll
        for (int ks = 0; ks < 4; ++ks) {
            bf16x8 cfr[4];
            #pragma unroll
            for (int fc = 0; fc < 4; ++fc) {
                const int row = wc + fc * 16 + l15;        // center row in tile
                int p = row * 256 + ks * 64 + kg * 16;
                p ^= ((row & 7) << 4);
                cfr[fc] = *(const bf16x8*)((const char*)sB[cur] + p);
            }
            #pragma unroll
            for (int fc = 0; fc < 4; ++fc)
                #pragma unroll
                for (int ff = 0; ff < 4; ++ff)
                    acc[fc][ff] = __builtin_amdgcn_mfma_f32_16x16x32_bf16(
                        cfr[fc], ffr[ks][ff], acc[fc][ff], 0, 0, 0);
        }

        // epilogue: loss already in acc; 3 VALU/elem + SALU count
        #pragma unroll
        for (int fc = 0; fc < 4; ++fc)
            #pragma unroll
            for (int ff = 0; ff < 4; ++ff)
                #pragma unroll
                for (int r = 0; r < 4; ++r) {
                    const float l = acc[fc][ff][r];
                    lsum += fmaxf(l, 0.0f);
                    wcnt += (unsigned int)__popcll(__ballot(l > 0.0f));
                }

        __syncthreads();
    }

    #pragma unroll
    for (int off = 32; off; off >>= 1) lsum += __shfl_xor(lsum, off);
    if (lane == 0) { sWsum[w] = lsum; sWcnt[w] = wcnt; }
    __syncthreads();
    if (tid == 0) {
        float s = 0.0f; unsigned int c = 0;
        #pragma unroll
        for (int i = 0; i < 8; ++i) { s += sWsum[i]; c += sWcnt[i]; }
        atomicAdd(acc_total, s);
        atomicAdd(acc_cnt, c);
    }
}

// ---- kernel 4: finalize ----
__global__ void k_finalize(const float* __restrict__ acc_total,
                           const unsigned int* __restrict__ acc_cnt,
                           float* __restrict__ out)
{
    const unsigned int c = *acc_cnt;
    out[0] = c ? (*acc_total / (float)c) : 0.0f;
}

extern "C" void kernel_launch(void* const* d_in, const int* in_sizes, int n_in,
                              void* d_out, int out_size, void* d_ws, size_t ws_size,
                              hipStream_t stream) {
    const float* feat    = (const float*)d_in[0];
    const float* centers = (const float*)d_in[1];
    const int*   labels  = (const int*)d_in[2];
    float* out = (float*)d_out;

    char* ws = (char*)d_ws;
    float*          acc_total = (float*)ws;                          // 4 B
    unsigned int*   acc_cnt   = (unsigned int*)(ws + 4);             // 4 B
    float*          t         = (float*)(ws + 1024);                 // 32 KB
    unsigned short* fb        = (unsigned short*)(ws + 131072);      // 2 MB
    unsigned short* cb        = (unsigned short*)(ws + 4*1024*1024); // 5.14 MB

    hipMemsetAsync(ws, 0, 8, stream);
    k_normalize<<<B_N / 4, 256, 0, stream>>>(feat, centers, labels, fb, t,
                                             acc_total, acc_cnt);
    k_convert<<<(CPAD * D_N / 4) / 256, 256, 0, stream>>>(centers, cb);
    dim3 grid(NSPLIT, 32);
    k_main<<<grid, 512, 0, stream>>>(fb, cb, t, acc_total, acc_cnt);
    k_finalize<<<1, 1, 0, stream>>>(acc_total, acc_cnt, out);
}

// Round 4
// 94.811 us; speedup vs baseline: 3.8165x; 3.8165x over previous
//
#include <hip/hip_runtime.h>

#define B_N 8192
#define C_N 20000
#define D_N 128
#define CPAD 20096              // 157 * 128
#define NTILES 157
#define NSPLIT 8                // tiles strided: tile = chunk + 8*j
#define MARGIN_F 0.15001125f    // 0.15 + (1/40000)*(0.6-0.15)

typedef __attribute__((ext_vector_type(8))) short bf16x8;
typedef __attribute__((ext_vector_type(4))) float f32x4;

typedef __attribute__((address_space(1))) const unsigned int GUint;
typedef __attribute__((address_space(3))) unsigned int LUint;

__device__ __forceinline__ unsigned short f2bf(float x) {
    union { float f; unsigned int u; } v; v.f = x;
    unsigned int r = v.u + 0x7fffu + ((v.u >> 16) & 1u);
    return (unsigned short)(r >> 16);
}
__device__ __forceinline__ float bf2f(unsigned short h) {
    union { unsigned int u; float f; } v; v.u = ((unsigned int)h) << 16; return v.f;
}

// ---- kernel 1: normalize features -> bf16, t[b] = MARGIN - posdot, per-row
// corrections to arrays (NO contended atomics — round-3 lesson: 8192
// same-address atomicAdds serialize to ~200us).
__global__ __launch_bounds__(256) void k_normalize(
    const float* __restrict__ feat, const float* __restrict__ centers,
    const int* __restrict__ labels, unsigned short* __restrict__ fb,
    float* __restrict__ t, float* __restrict__ corr_s, unsigned int* __restrict__ corr_c)
{
    const int lane = threadIdx.x & 63;
    const int row  = blockIdx.x * 4 + (threadIdx.x >> 6);   // wave per row
    const float2 fv = *(const float2*)(feat + (size_t)row * D_N + lane * 2);
    float ss = fv.x * fv.x + fv.y * fv.y;
    #pragma unroll
    for (int off = 32; off; off >>= 1) ss += __shfl_xor(ss, off);
    const float scale = 1.0f / fmaxf(sqrtf(ss), 1e-12f);
    const float a = fv.x * scale, b = fv.y * scale;
    ushort2 o; o.x = f2bf(a); o.y = f2bf(b);
    *(ushort2*)(fb + (size_t)row * D_N + lane * 2) = o;

    const int lab = labels[row];
    const float2 cv = *(const float2*)(centers + (size_t)lab * D_N + lane * 2);
    float pd = a * cv.x + b * cv.y;                                        // fp32 dot
    float pb = bf2f(o.x) * bf2f(f2bf(cv.x)) + bf2f(o.y) * bf2f(f2bf(cv.y)); // bf16 dot
    #pragma unroll
    for (int off = 32; off; off >>= 1) {
        pd += __shfl_xor(pd, off);
        pb += __shfl_xor(pb, off);
    }
    if (lane == 0) {
        const float tb = MARGIN_F - pd;
        t[row] = tb;
        float cs = fmaxf(tb + pb, 0.0f);                 // label-column term
        unsigned int cc = (tb + pb > 0.0f) ? 1u : 0u;
        if (tb > 0.0f) { cs += 96.0f * tb; cc += 96u; }  // 96 zero-pad columns
        corr_s[row] = cs;
        corr_c[row] = cc;
    }
}

// ---- kernel 2: centers -> bf16, zero-pad rows [20000,20096) ----
__global__ __launch_bounds__(256) void k_convert(
    const float* __restrict__ centers, unsigned short* __restrict__ cb)
{
    const int idx = blockIdx.x * 256 + threadIdx.x;
    const int e = idx * 4;
    const int row = e >> 7;
    ushort4 o;
    if (row < C_N) {
        const float4 v = *(const float4*)(centers + e);
        o.x = f2bf(v.x); o.y = f2bf(v.y); o.z = f2bf(v.z); o.w = f2bf(v.w);
    } else {
        o.x = 0; o.y = 0; o.z = 0; o.w = 0;
    }
    *(ushort4*)(cb + e) = o;
}

// ---- kernel 3: main. 256 feature rows/block (in regs, B-operand), centers in a
// 3-deep LDS ring (A-operand). Raw s_barrier + counted vmcnt: tile j+1/j+2
// loads stay in flight across barriers (T3+T4). 1 block/CU by design.
__global__ __launch_bounds__(512, 2) void k_main(
    const unsigned short* __restrict__ fb,   // [8192][128] bf16 normalized features
    const unsigned short* __restrict__ cb,   // [20096][128] bf16 centers, zero-padded
    const float* __restrict__ t,             // [8192]
    float* __restrict__ acc_total, unsigned int* __restrict__ acc_cnt)
{
    __shared__ __align__(16) unsigned short sB[3][128 * 128];   // 3 x 32 KB ring
    __shared__ float sWsum[8];
    __shared__ unsigned int sWcnt[8];

    const int tid  = threadIdx.x;
    const int lane = tid & 63;
    const int w    = tid >> 6;            // wave 0..7
    const int chunk   = blockIdx.x;       // 0..7, tiles chunk + 8*j
    const int rowbase = blockIdx.y * 256; // feature row block
    const int nt = (156 - chunk) / 8 + 1; // 20 or 19 (always >= 3)

    const int wc = (w & 1) * 64;          // wave center-row offset in tile
    const int wf = (w >> 1) * 64;         // wave feature offset
    const int l15 = lane & 15;
    const int kg  = lane >> 4;

    // ---- center staging: linear LDS dest + involution-swizzled global source ----
    const char* gB0 = (const char*)cb;
    auto STAGE = [&](int buf, int tile) {
        const char* gB = gB0 + (size_t)tile * 32768;
        const int base = w * 4096;
        #pragma unroll
        for (int i = 0; i < 4; ++i) {
            const int loff = base + i * 1024;              // wave-uniform LDS base
            const int x = loff + lane * 16;
            const int sx = x ^ (((x >> 8) & 7) << 4);      // involution
            __builtin_amdgcn_global_load_lds((GUint*)(gB + sx),
                (LUint*)((char*)sB[buf] + loff), 16, 0, 0);
        }
    };

    // Issue ring-fill FIRST so these are the oldest vmcnt entries.
    STAGE(0, chunk);
    STAGE(1, chunk + 8);
    STAGE(2, chunk + 16);

    // ---- prologue: feature fragments + t values -> registers (younger loads) ----
    bf16x8 ffr[4][4];                     // [ks][ff]
    float tvr[4];
    #pragma unroll
    for (int ff = 0; ff < 4; ++ff) {
        const int m = rowbase + wf + ff * 16 + l15;
        const unsigned short* src = fb + (size_t)m * D_N + kg * 8;
        #pragma unroll
        for (int ks = 0; ks < 4; ++ks)
            ffr[ks][ff] = *(const bf16x8*)(src + ks * 32);
        tvr[ff] = t[m];
    }

    float lsum = 0.0f;
    unsigned int wcnt = 0;

    auto COMPUTE = [&](int cur) {
        f32x4 acc[4][4];                  // [fc][ff]
        #pragma unroll
        for (int fc = 0; fc < 4; ++fc)
            #pragma unroll
            for (int ff = 0; ff < 4; ++ff)
                #pragma unroll
                for (int r = 0; r < 4; ++r)
                    acc[fc][ff][r] = tvr[ff];

        const char* sbase = (const char*)sB[cur];
        #pragma unroll
        for (int ks = 0; ks < 4; ++ks) {
            bf16x8 cfr[4];
            #pragma unroll
            for (int fc = 0; fc < 4; ++fc) {
                const int row = wc + fc * 16 + l15;        // center row in tile
                int p = row * 256 + ks * 64 + kg * 16;
                p ^= ((row & 7) << 4);
                cfr[fc] = *(const bf16x8*)(sbase + p);
            }
            #pragma unroll
            for (int fc = 0; fc < 4; ++fc)
                #pragma unroll
                for (int ff = 0; ff < 4; ++ff)
                    acc[fc][ff] = __builtin_amdgcn_mfma_f32_16x16x32_bf16(
                        cfr[fc], ffr[ks][ff], acc[fc][ff], 0, 0, 0);
        }

        // epilogue: loss already in acc; VALU sum + SALU ballot-count
        #pragma unroll
        for (int fc = 0; fc < 4; ++fc)
            #pragma unroll
            for (int ff = 0; ff < 4; ++ff)
                #pragma unroll
                for (int r = 0; r < 4; ++r) {
                    const float l = acc[fc][ff][r];
                    lsum += fmaxf(l, 0.0f);
                    wcnt += (unsigned int)__popcll(__ballot(l > 0.0f));
                }
    };

#define RING_BAR() do {                                   \
        __builtin_amdgcn_sched_barrier(0);                \
        __builtin_amdgcn_s_barrier();                     \
        __builtin_amdgcn_sched_barrier(0);                \
    } while (0)

#define RING_ITER(J, VM) do {                             \
        asm volatile("s_waitcnt vmcnt(" #VM ")" ::: "memory"); \
        RING_BAR();                                       \
        const int cur_ = (J) % 3;                         \
        COMPUTE(cur_);                                    \
        RING_BAR();                                       \
        if ((J) + 3 < nt) STAGE(cur_, chunk + ((J) + 3) * 8); \
    } while (0)

    for (int j = 0; j + 2 < nt; ++j) RING_ITER(j, 8);
    RING_ITER(nt - 2, 4);
    RING_ITER(nt - 1, 0);

#undef RING_ITER
#undef RING_BAR

    #pragma unroll
    for (int off = 32; off; off >>= 1) lsum += __shfl_xor(lsum, off);
    if (lane == 0) { sWsum[w] = lsum; sWcnt[w] = wcnt; }
    __syncthreads();
    if (tid == 0) {
        float s = 0.0f; unsigned int c = 0;
        #pragma unroll
        for (int i = 0; i < 8; ++i) { s += sWsum[i]; c += sWcnt[i]; }
        atomicAdd(acc_total, s);
        atomicAdd(acc_cnt, c);
    }
}

// ---- kernel 4: reduce corrections, finalize ----
__global__ __launch_bounds__(256) void k_finalize(
    const float* __restrict__ acc_total, const unsigned int* __restrict__ acc_cnt,
    const float* __restrict__ corr_s, const unsigned int* __restrict__ corr_c,
    float* __restrict__ out)
{
    __shared__ float ss[4];
    __shared__ unsigned int sc[4];
    const int tid = threadIdx.x;
    const int lane = tid & 63;
    const int w = tid >> 6;
    float cs = 0.0f; unsigned int cc = 0;
    for (int i = tid; i < B_N; i += 256) { cs += corr_s[i]; cc += corr_c[i]; }
    #pragma unroll
    for (int off = 32; off; off >>= 1) {
        cs += __shfl_xor(cs, off);
        cc += __shfl_xor(cc, off);
    }
    if (lane == 0) { ss[w] = cs; sc[w] = cc; }
    __syncthreads();
    if (tid == 0) {
        const float S = acc_total[0] - (ss[0] + ss[1] + ss[2] + ss[3]);
        const unsigned int C = acc_cnt[0] - (sc[0] + sc[1] + sc[2] + sc[3]);
        out[0] = C ? (S / (float)C) : 0.0f;
    }
}

extern "C" void kernel_launch(void* const* d_in, const int* in_sizes, int n_in,
                              void* d_out, int out_size, void* d_ws, size_t ws_size,
                              hipStream_t stream) {
    const float* feat    = (const float*)d_in[0];
    const float* centers = (const float*)d_in[1];
    const int*   labels  = (const int*)d_in[2];
    float* out = (float*)d_out;

    char* ws = (char*)d_ws;
    float*          acc_total = (float*)ws;                          // 4 B
    unsigned int*   acc_cnt   = (unsigned int*)(ws + 4);             // 4 B
    float*          t         = (float*)(ws + 1024);                 // 32 KB
    float*          corr_s    = (float*)(ws + 65536);                // 32 KB
    unsigned int*   corr_c    = (unsigned int*)(ws + 98304);         // 32 KB
    unsigned short* fb        = (unsigned short*)(ws + 131072);      // 2 MB
    unsigned short* cb        = (unsigned short*)(ws + 4*1024*1024); // 5.14 MB

    hipMemsetAsync(ws, 0, 8, stream);
    k_normalize<<<B_N / 4, 256, 0, stream>>>(feat, centers, labels, fb, t,
                                             corr_s, corr_c);
    k_convert<<<(CPAD * D_N / 4) / 256, 256, 0, stream>>>(centers, cb);
    dim3 grid(NSPLIT, 32);
    k_main<<<grid, 512, 0, stream>>>(fb, cb, t, acc_total, acc_cnt);
    k_finalize<<<1, 256, 0, stream>>>(acc_total, acc_cnt, corr_s, corr_c, out);
}